// Round 2
// baseline (577.795 us; speedup 1.0000x reference)
//
#include <hip/hip_runtime.h>

typedef __attribute__((ext_vector_type(8))) short short8;
typedef __attribute__((ext_vector_type(4))) short short4v;
typedef __attribute__((ext_vector_type(4))) float float4a;

#define MFMA16(a, b, c) __builtin_amdgcn_mfma_f32_16x16x32_bf16(a, b, c, 0, 0, 0)

static __device__ __forceinline__ short f2bf(float f) {
  unsigned u = __builtin_bit_cast(unsigned, f);
  u += 0x7fff + ((u >> 16) & 1);   // RNE
  return (short)(u >> 16);
}
static __device__ __forceinline__ float bf2f(short s) {
  unsigned u = ((unsigned)(unsigned short)s) << 16;
  return __builtin_bit_cast(float, u);
}

// f32 -> bf16 (RNE), 4 elems/thread
__global__ __launch_bounds__(256) void cvt_k(const float* __restrict__ in,
                                             short* __restrict__ out, int n4) {
  int i = blockIdx.x * 256 + threadIdx.x;
  if (i < n4) {
    float4a v = ((const float4a*)in)[i];
    short4v o;
    o.x = f2bf(v.x); o.y = f2bf(v.y); o.z = f2bf(v.z); o.w = f2bf(v.w);
    ((short4v*)out)[i] = o;
  }
}

// C[m,n] = sum_k A[m,k] * Bw[n,k].  M=4096, N=1024, K=1024. bf16 in.
// Wave computes a 16x64 output tile. mode selects output layout:
//   0: Qp/Kp  bf16 out[((b*8+h)*1024+s)*128+d]
//   1: Vt     bf16 out[(b*8+h)*131072 + d*1024 + s]   (transposed V)
//   2: plain  f32  out[m*1024+n]
__global__ __launch_bounds__(256) void gemm_bt(const short* __restrict__ A,
                                               const short* __restrict__ Bw,
                                               void* __restrict__ C,
                                               int mode) {
  int lane = threadIdx.x & 63;
  int wid  = threadIdx.x >> 6;
  int gw   = blockIdx.x * 4 + wid;      // 4096 waves
  int mt   = gw & 255;                  // 256 m-tiles of 16
  int nt   = gw >> 8;                   // 16 n-tiles of 64
  int l15  = lane & 15, quad = lane >> 4;

  const short* arow = A + (mt * 16 + l15) * 1024 + quad * 8;
  float4a acc[4] = {{0,0,0,0},{0,0,0,0},{0,0,0,0},{0,0,0,0}};
  for (int kc = 0; kc < 1024; kc += 32) {
    short8 a = *(const short8*)(arow + kc);
#pragma unroll
    for (int t = 0; t < 4; ++t) {
      const short* brow = Bw + (nt * 64 + t * 16 + l15) * 1024 + kc + quad * 8;
      short8 b = *(const short8*)brow;
      acc[t] = MFMA16(a, b, acc[t]);
    }
  }
#pragma unroll
  for (int t = 0; t < 4; ++t) {
    int n = nt * 64 + t * 16 + l15;
#pragma unroll
    for (int r = 0; r < 4; ++r) {
      int m = mt * 16 + quad * 4 + r;
      float v = acc[t][r];
      if (mode == 2) {
        ((float*)C)[m * 1024 + n] = v;
      } else {
        int b = m >> 10, s = m & 1023, h = n >> 7, d = n & 127;
        int idx = (mode == 0) ? ((((b * 8 + h) * 1024) + s) * 128 + d)
                              : ((b * 8 + h) * 131072 + d * 1024 + s);
        ((short*)C)[idx] = f2bf(v);
      }
    }
  }
}

// Qrel[bh, q, r] = sum_d Qp[bh,q,d] * rel[h,r,d]   (bf16 out)
__global__ __launch_bounds__(256) void qrel_k(const short* __restrict__ Qp,
                                              const short* __restrict__ rel,
                                              short* __restrict__ Qrel) {
  int lane = threadIdx.x & 63, wid = threadIdx.x >> 6;
  int gw = blockIdx.x * 4 + wid;        // 34816 waves
  int bh = gw / 1088;
  int rem = gw - bh * 1088;
  int mt = rem / 17;
  int nt = rem - mt * 17;
  int l15 = lane & 15, quad = lane >> 4;
  int h = bh & 7;

  const short* arow = Qp + bh * 131072 + (mt * 16 + l15) * 128 + quad * 8;
  int col = nt * 16 + l15;
  int colc = col > 256 ? 256 : col;     // clamp to avoid OOB read; store masked
  const short* brow = rel + (h * 257 + colc) * 128 + quad * 8;

  float4a acc = {0, 0, 0, 0};
#pragma unroll
  for (int kc = 0; kc < 128; kc += 32) {
    short8 a = *(const short8*)(arow + kc);
    short8 b = *(const short8*)(brow + kc);
    acc = MFMA16(a, b, acc);
  }
  if (col < 257) {
#pragma unroll
    for (int r = 0; r < 4; ++r) {
      int q = mt * 16 + quad * 4 + r;
      Qrel[bh * 263168 + q * 257 + col] = f2bf(acc[r]);
    }
  }
}

// Flash-style banded attention. One wave per 16 queries; k-chunks of 32.
// Writes O2[(b*1024+q)*1024 + d*8 + h]  (feature = d*H+h, per reference transpose).
__global__ __launch_bounds__(256) void attn_k(const short* __restrict__ Qp,
                                              const short* __restrict__ Kp,
                                              const short* __restrict__ Vt,
                                              const short* __restrict__ Qrel,
                                              const unsigned char* __restrict__ kpm,
                                              short* __restrict__ O2) {
  __shared__ short plds[4][16][40];     // P tile per wave, padded stride
  int lane = threadIdx.x & 63, wid = threadIdx.x >> 6;
  int bh = blockIdx.x >> 4;
  int qblk = blockIdx.x & 15;
  int q0 = qblk * 64 + wid * 16;
  int l15 = lane & 15, quad = lane >> 4;
  int b = bh >> 3, h = bh & 7;

  short8 aq[4];
  const short* qrow = Qp + bh * 131072 + (q0 + l15) * 128 + quad * 8;
#pragma unroll
  for (int kc = 0; kc < 4; ++kc) aq[kc] = *(const short8*)(qrow + kc * 32);

  float4a O[8];
#pragma unroll
  for (int i = 0; i < 8; ++i) O[i] = (float4a){0, 0, 0, 0};
  float m_[4], l_[4];
#pragma unroll
  for (int r = 0; r < 4; ++r) { m_[r] = -INFINITY; l_[r] = 0.f; }

  int klo = q0 - 256; if (klo < 0) klo = 0; klo &= ~31;
  int khi = q0 + 272; if (khi > 1024) khi = 1024; khi = (khi + 31) & ~31;
  const float sc = 0.08838834764831845f;  // 1/sqrt(128)

  const short* kbase = Kp + bh * 131072 + quad * 8;
  const short* vbase0 = Vt + bh * 131072 + quad * 8;
  const short* qrbase = Qrel + bh * 263168;

  for (int k0 = klo; k0 < khi; k0 += 32) {
    float4a s0 = {0,0,0,0}, s1 = {0,0,0,0};
#pragma unroll
    for (int kc = 0; kc < 4; ++kc) {
      short8 b0 = *(const short8*)(kbase + (k0 + l15) * 128 + kc * 32);
      short8 b1 = *(const short8*)(kbase + (k0 + 16 + l15) * 128 + kc * 32);
      s0 = MFMA16(aq[kc], b0, s0);
      s1 = MFMA16(aq[kc], b1, s1);
    }
    float alpha[4];
#pragma unroll
    for (int r = 0; r < 4; ++r) {
      int q = q0 + quad * 4 + r;
      int ka = k0 + l15, kb2 = k0 + 16 + l15;
      int d0 = ka - q, d1 = kb2 - q;
      int r0 = d0 < -128 ? 0 : (d0 > 128 ? 256 : d0 + 128);
      int r1 = d1 < -128 ? 0 : (d1 > 128 ? 256 : d1 + 128);
      const short* qr = qrbase + q * 257;
      float v0 = (s0[r] + bf2f(qr[r0])) * sc;
      float v1 = (s1[r] + bf2f(qr[r1])) * sc;
      if (d0 < -256 || d0 > 256 || kpm[b * 1024 + ka])  v0 = -INFINITY;
      if (d1 < -256 || d1 > 256 || kpm[b * 1024 + kb2]) v1 = -INFINITY;
      float rm = fmaxf(v0, v1);
#pragma unroll
      for (int off = 1; off < 16; off <<= 1) rm = fmaxf(rm, __shfl_xor(rm, off, 64));
      float mnew = fmaxf(m_[r], rm);
      float a_, p0, p1;
      if (mnew == -INFINITY) { a_ = 1.f; p0 = 0.f; p1 = 0.f; }
      else {
        a_ = __expf(m_[r] - mnew);     // m_ = -inf -> 0, correct
        p0 = __expf(v0 - mnew);        // v = -inf -> 0
        p1 = __expf(v1 - mnew);
      }
      float ps = p0 + p1;
#pragma unroll
      for (int off = 1; off < 16; off <<= 1) ps += __shfl_xor(ps, off, 64);
      l_[r] = l_[r] * a_ + ps;
      m_[r] = mnew;
      alpha[r] = a_;
      s0[r] = p0; s1[r] = p1;
    }
#pragma unroll
    for (int dt = 0; dt < 8; ++dt)
#pragma unroll
      for (int r = 0; r < 4; ++r) O[dt][r] *= alpha[r];
    // P (C-layout) -> LDS -> A-layout fragment
#pragma unroll
    for (int r = 0; r < 4; ++r) {
      plds[wid][quad * 4 + r][l15]      = f2bf(s0[r]);
      plds[wid][quad * 4 + r][16 + l15] = f2bf(s1[r]);
    }
    short8 ap = *(const short8*)&plds[wid][l15][quad * 8];
#pragma unroll
    for (int dt = 0; dt < 8; ++dt) {
      short8 bv = *(const short8*)(vbase0 + (dt * 16 + l15) * 1024 + k0);
      O[dt] = MFMA16(ap, bv, O[dt]);
    }
  }
  // epilogue: O2 feature index = d*8 + h
#pragma unroll
  for (int r = 0; r < 4; ++r) {
    int q = q0 + quad * 4 + r;
    float inv = 1.f / l_[r];
    short* orow = O2 + (b * 1024 + q) * 1024 + h;
#pragma unroll
    for (int dt = 0; dt < 8; ++dt) {
      int d = dt * 16 + l15;
      orow[d * 8] = f2bf(O[dt][r] * inv);
    }
  }
}

extern "C" void kernel_launch(void* const* d_in, const int* in_sizes, int n_in,
                              void* d_out, int out_size, void* d_ws, size_t ws_size,
                              hipStream_t stream) {
  const float* Q   = (const float*)d_in[0];
  const float* K   = (const float*)d_in[1];
  const float* V   = (const float*)d_in[2];
  const unsigned char* kpm = (const unsigned char*)d_in[4];
  const float* Wq  = (const float*)d_in[5];
  const float* Wk  = (const float*)d_in[6];
  const float* Wv  = (const float*)d_in[7];
  const float* Wo  = (const float*)d_in[8];
  const float* rel = (const float*)d_in[9];
  float* out = (float*)d_out;

  short* ws = (short*)d_ws;
  short* Qb   = ws;                      // 4194304
  short* Kb   = Qb + 4194304;
  short* Vb   = Kb + 4194304;
  short* Wqb  = Vb + 4194304;            // 1048576
  short* Wkb  = Wqb + 1048576;
  short* Wvb  = Wkb + 1048576;
  short* Wob  = Wvb + 1048576;
  short* relb = Wob + 1048576;           // 263168
  short* Qp   = relb + 263168;           // 4194304
  short* Kp   = Qp + 4194304;
  short* Vt   = Kp + 4194304;
  short* Qrel = Vt + 4194304;            // 8421376
  short* O2   = Qrel + 8421376;          // 4194304

  cvt_k<<<dim3(4096), dim3(256), 0, stream>>>(Q, Qb, 1048576);
  cvt_k<<<dim3(4096), dim3(256), 0, stream>>>(K, Kb, 1048576);
  cvt_k<<<dim3(4096), dim3(256), 0, stream>>>(V, Vb, 1048576);
  cvt_k<<<dim3(1024), dim3(256), 0, stream>>>(Wq, Wqb, 262144);
  cvt_k<<<dim3(1024), dim3(256), 0, stream>>>(Wk, Wkb, 262144);
  cvt_k<<<dim3(1024), dim3(256), 0, stream>>>(Wv, Wvb, 262144);
  cvt_k<<<dim3(1024), dim3(256), 0, stream>>>(Wo, Wob, 262144);
  cvt_k<<<dim3(257),  dim3(256), 0, stream>>>(rel, relb, 65792);

  gemm_bt<<<dim3(1024), dim3(256), 0, stream>>>(Qb, Wqb, Qp, 0);
  gemm_bt<<<dim3(1024), dim3(256), 0, stream>>>(Kb, Wkb, Kp, 0);
  gemm_bt<<<dim3(1024), dim3(256), 0, stream>>>(Vb, Wvb, Vt, 1);
  qrel_k<<<dim3(8704), dim3(256), 0, stream>>>(Qp, relb, Qrel);
  attn_k<<<dim3(512), dim3(256), 0, stream>>>(Qp, Kp, Vt, Qrel, kpm, O2);
  gemm_bt<<<dim3(1024), dim3(256), 0, stream>>>(O2, Wob, out, 2);
}

// Round 3
// 310.354 us; speedup vs baseline: 1.8617x; 1.8617x over previous
//
#include <hip/hip_runtime.h>

typedef __attribute__((ext_vector_type(8))) short short8;
typedef __attribute__((ext_vector_type(4))) short short4v;
typedef __attribute__((ext_vector_type(4))) float float4a;

#define MFMA16(a, b, c) __builtin_amdgcn_mfma_f32_16x16x32_bf16(a, b, c, 0, 0, 0)

static __device__ __forceinline__ short f2bf(float f) {
  unsigned u = __builtin_bit_cast(unsigned, f);
  u += 0x7fff + ((u >> 16) & 1);   // RNE
  return (short)(u >> 16);
}
static __device__ __forceinline__ float bf2f(short s) {
  unsigned u = ((unsigned)(unsigned short)s) << 16;
  return __builtin_bit_cast(float, u);
}

// async global->LDS, 16 B per lane. LDS dest must be wave-uniform base + lane*16.
static __device__ __forceinline__ void gl2lds(const short* g, short* l) {
  __builtin_amdgcn_global_load_lds(
      (const __attribute__((address_space(1))) void*)g,
      (__attribute__((address_space(3))) void*)l,
      16, 0, 0);
}

// ---- fused f32->bf16 conversion for all 8 tensors ----
struct Cvt8 { const float* in[8]; short* out[8]; };
// segs 0-2: 4096 blocks each (Q,K,V); 3-6: 1024 each (W*); 7: 257 (rel)
__global__ __launch_bounds__(256) void cvt8_k(Cvt8 a) {
  int b = blockIdx.x, seg, rb;
  if (b < 12288)      { seg = b >> 12;               rb = b & 4095; }
  else if (b < 16384) { seg = 3 + ((b - 12288) >> 10); rb = (b - 12288) & 1023; }
  else                { seg = 7;                     rb = b - 16384; }
  int i = rb * 256 + threadIdx.x;
  float4a v = ((const float4a*)a.in[seg])[i];
  short4v o;
  o.x = f2bf(v.x); o.y = f2bf(v.y); o.z = f2bf(v.z); o.w = f2bf(v.w);
  ((short4v*)a.out[seg])[i] = o;
}

// ---- m97-style tiled GEMM: C = A @ W^T, M=4096 (per seg), N=1024, K=1024 ----
// 128x128 tile, BK=32, 256 thr (2x2 waves of 64x64). Fused Q/K/V projections.
// seg 0: Qp  bf16 [((b*8+h)*1024+s)*128+d]
// seg 1: Kp  same layout
// seg 2: Vt  bf16 [(b*8+h)*131072 + d*1024 + s]   (transposed V)
__global__ __launch_bounds__(256) void gemm_qkv(
    const short* __restrict__ Qb, const short* __restrict__ Kb, const short* __restrict__ Vb,
    const short* __restrict__ Wq, const short* __restrict__ Wk, const short* __restrict__ Wv,
    short* __restrict__ Qp, short* __restrict__ Kp, short* __restrict__ Vt) {
  __shared__ short As[128 * 32];
  __shared__ short Bs[128 * 32];
  int seg = blockIdx.x >> 8, bid = blockIdx.x & 255;
  const short* A = seg == 0 ? Qb : (seg == 1 ? Kb : Vb);
  const short* W = seg == 0 ? Wq : (seg == 1 ? Wk : Wv);
  int mt = bid >> 3, nt = bid & 7;
  int m0 = mt * 128, n0 = nt * 128;
  int lane = threadIdx.x & 63, wid = threadIdx.x >> 6;
  int l15 = lane & 15, quad = lane >> 4;
  int wm = wid & 1, wn = wid >> 1;

  // staging: wave wid covers rows wid*32..wid*32+31 (2 insts of 16 rows)
  int lrow = lane >> 2, lcol = (lane & 3) * 8;
  const short* gA = A + (m0 + wid * 32 + lrow) * 1024 + lcol;
  const short* gB = W + (n0 + wid * 32 + lrow) * 1024 + lcol;
  short* lA = As + (wid * 32) * 32 + lane * 8;
  short* lB = Bs + (wid * 32) * 32 + lane * 8;

  float4a acc[4][4];
#pragma unroll
  for (int i = 0; i < 4; ++i)
#pragma unroll
    for (int j = 0; j < 4; ++j) acc[i][j] = (float4a){0, 0, 0, 0};

  for (int kc = 0; kc < 1024; kc += 32) {
    __syncthreads();
    gl2lds(gA + kc, lA);
    gl2lds(gA + 16 * 1024 + kc, lA + 16 * 32);
    gl2lds(gB + kc, lB);
    gl2lds(gB + 16 * 1024 + kc, lB + 16 * 32);
    __syncthreads();
    short8 af[4], bfr[4];
#pragma unroll
    for (int i = 0; i < 4; ++i)
      af[i] = *(const short8*)&As[(wm * 64 + i * 16 + l15) * 32 + quad * 8];
#pragma unroll
    for (int j = 0; j < 4; ++j)
      bfr[j] = *(const short8*)&Bs[(wn * 64 + j * 16 + l15) * 32 + quad * 8];
#pragma unroll
    for (int i = 0; i < 4; ++i)
#pragma unroll
      for (int j = 0; j < 4; ++j) acc[i][j] = MFMA16(af[i], bfr[j], acc[i][j]);
  }

#pragma unroll
  for (int i = 0; i < 4; ++i)
#pragma unroll
    for (int j = 0; j < 4; ++j)
#pragma unroll
      for (int r = 0; r < 4; ++r) {
        int m = m0 + wm * 64 + i * 16 + quad * 4 + r;
        int n = n0 + wn * 64 + j * 16 + l15;
        int bb = m >> 10, s = m & 1023, hh = n >> 7, d = n & 127;
        short v = f2bf(acc[i][j][r]);
        if (seg == 0)      Qp[(((bb * 8 + hh) * 1024) + s) * 128 + d] = v;
        else if (seg == 1) Kp[(((bb * 8 + hh) * 1024) + s) * 128 + d] = v;
        else               Vt[(bb * 8 + hh) * 131072 + d * 1024 + s] = v;
      }
}

// ---- output projection: out(f32) = O2 @ Wo^T, same tiled structure ----
__global__ __launch_bounds__(256) void gemm_o(const short* __restrict__ A,
                                              const short* __restrict__ W,
                                              float* __restrict__ C) {
  __shared__ short As[128 * 32];
  __shared__ short Bs[128 * 32];
  int bid = blockIdx.x;
  int mt = bid >> 3, nt = bid & 7;
  int m0 = mt * 128, n0 = nt * 128;
  int lane = threadIdx.x & 63, wid = threadIdx.x >> 6;
  int l15 = lane & 15, quad = lane >> 4;
  int wm = wid & 1, wn = wid >> 1;

  int lrow = lane >> 2, lcol = (lane & 3) * 8;
  const short* gA = A + (m0 + wid * 32 + lrow) * 1024 + lcol;
  const short* gB = W + (n0 + wid * 32 + lrow) * 1024 + lcol;
  short* lA = As + (wid * 32) * 32 + lane * 8;
  short* lB = Bs + (wid * 32) * 32 + lane * 8;

  float4a acc[4][4];
#pragma unroll
  for (int i = 0; i < 4; ++i)
#pragma unroll
    for (int j = 0; j < 4; ++j) acc[i][j] = (float4a){0, 0, 0, 0};

  for (int kc = 0; kc < 1024; kc += 32) {
    __syncthreads();
    gl2lds(gA + kc, lA);
    gl2lds(gA + 16 * 1024 + kc, lA + 16 * 32);
    gl2lds(gB + kc, lB);
    gl2lds(gB + 16 * 1024 + kc, lB + 16 * 32);
    __syncthreads();
    short8 af[4], bfr[4];
#pragma unroll
    for (int i = 0; i < 4; ++i)
      af[i] = *(const short8*)&As[(wm * 64 + i * 16 + l15) * 32 + quad * 8];
#pragma unroll
    for (int j = 0; j < 4; ++j)
      bfr[j] = *(const short8*)&Bs[(wn * 64 + j * 16 + l15) * 32 + quad * 8];
#pragma unroll
    for (int i = 0; i < 4; ++i)
#pragma unroll
      for (int j = 0; j < 4; ++j) acc[i][j] = MFMA16(af[i], bfr[j], acc[i][j]);
  }

#pragma unroll
  for (int i = 0; i < 4; ++i)
#pragma unroll
    for (int j = 0; j < 4; ++j)
#pragma unroll
      for (int r = 0; r < 4; ++r) {
        int m = m0 + wm * 64 + i * 16 + quad * 4 + r;
        int n = n0 + wn * 64 + j * 16 + l15;
        C[m * 1024 + n] = acc[i][j][r];
      }
}

// Qrel[bh, q, r] = sum_d Qp[bh,q,d] * rel[h,r,d]   (bf16 out)
__global__ __launch_bounds__(256) void qrel_k(const short* __restrict__ Qp,
                                              const short* __restrict__ rel,
                                              short* __restrict__ Qrel) {
  int lane = threadIdx.x & 63, wid = threadIdx.x >> 6;
  int gw = blockIdx.x * 4 + wid;        // 34816 waves
  int bh = gw / 1088;
  int rem = gw - bh * 1088;
  int mt = rem / 17;
  int nt = rem - mt * 17;
  int l15 = lane & 15, quad = lane >> 4;
  int h = bh & 7;

  const short* arow = Qp + bh * 131072 + (mt * 16 + l15) * 128 + quad * 8;
  int col = nt * 16 + l15;
  int colc = col > 256 ? 256 : col;
  const short* brow = rel + (h * 257 + colc) * 128 + quad * 8;

  float4a acc = {0, 0, 0, 0};
#pragma unroll
  for (int kc = 0; kc < 128; kc += 32) {
    short8 a = *(const short8*)(arow + kc);
    short8 b = *(const short8*)(brow + kc);
    acc = MFMA16(a, b, acc);
  }
  if (col < 257) {
#pragma unroll
    for (int r = 0; r < 4; ++r) {
      int q = mt * 16 + quad * 4 + r;
      Qrel[bh * 263168 + q * 257 + col] = f2bf(acc[r]);
    }
  }
}

// Banded attention, no-max flash (scores bounded: |s| << 88, fp32 exp safe),
// deferred l-reduction. One wave per 16 queries; k-chunks of 32.
__global__ __launch_bounds__(256) void attn_k(const short* __restrict__ Qp,
                                              const short* __restrict__ Kp,
                                              const short* __restrict__ Vt,
                                              const short* __restrict__ Qrel,
                                              const unsigned char* __restrict__ kpm,
                                              short* __restrict__ O2) {
  __shared__ short plds[4][16][40];
  int lane = threadIdx.x & 63, wid = threadIdx.x >> 6;
  int bh = blockIdx.x >> 4, qblk = blockIdx.x & 15;
  int q0 = qblk * 64 + wid * 16;
  int l15 = lane & 15, quad = lane >> 4;
  int b = bh >> 3, h = bh & 7;

  short8 aq[4];
  const short* qrow = Qp + bh * 131072 + (q0 + l15) * 128 + quad * 8;
#pragma unroll
  for (int kc = 0; kc < 4; ++kc) aq[kc] = *(const short8*)(qrow + kc * 32);

  float4a O[8];
#pragma unroll
  for (int i = 0; i < 8; ++i) O[i] = (float4a){0, 0, 0, 0};
  float lsum[4] = {0.f, 0.f, 0.f, 0.f};

  int klo = q0 - 256; if (klo < 0) klo = 0; klo &= ~31;
  int khi = q0 + 272; if (khi > 1024) khi = 1024; khi = (khi + 31) & ~31;
  const float sc = 0.08838834764831845f;  // 1/sqrt(128)

  const short* kbase = Kp + bh * 131072 + quad * 8;
  const short* vbase = Vt + bh * 131072 + quad * 8;
  const short* qrbase = Qrel + bh * 263168;
  const unsigned char* pmrow = kpm + b * 1024;

  for (int k0 = klo; k0 < khi; k0 += 32) {
    // issue all loads first: K, V, mask, rel-gathers (overlap with MFMA latency)
    short8 kb0[4], kb1[4];
#pragma unroll
    for (int kc = 0; kc < 4; ++kc) {
      kb0[kc] = *(const short8*)(kbase + (k0 + l15) * 128 + kc * 32);
      kb1[kc] = *(const short8*)(kbase + (k0 + 16 + l15) * 128 + kc * 32);
    }
    short8 bv[8];
#pragma unroll
    for (int dt = 0; dt < 8; ++dt)
      bv[dt] = *(const short8*)(vbase + (dt * 16 + l15) * 1024 + k0);
    int pm0 = pmrow[k0 + l15], pm1 = pmrow[k0 + 16 + l15];
    float qr0[4], qr1[4];
    int msk0[4], msk1[4];
#pragma unroll
    for (int r = 0; r < 4; ++r) {
      int q = q0 + quad * 4 + r;
      int d0 = k0 + l15 - q, d1 = d0 + 16;
      int r0 = d0 < -128 ? 0 : (d0 > 128 ? 256 : d0 + 128);
      int r1 = d1 < -128 ? 0 : (d1 > 128 ? 256 : d1 + 128);
      const short* qr = qrbase + q * 257;
      qr0[r] = bf2f(qr[r0]);
      qr1[r] = bf2f(qr[r1]);
      msk0[r] = (d0 < -256) | (d0 > 256) | pm0;
      msk1[r] = (d1 < -256) | (d1 > 256) | pm1;
    }
    float4a s0 = {0, 0, 0, 0}, s1 = {0, 0, 0, 0};
#pragma unroll
    for (int kc = 0; kc < 4; ++kc) {
      s0 = MFMA16(aq[kc], kb0[kc], s0);
      s1 = MFMA16(aq[kc], kb1[kc], s1);
    }
#pragma unroll
    for (int r = 0; r < 4; ++r) {
      float p0 = msk0[r] ? 0.f : __expf((s0[r] + qr0[r]) * sc);
      float p1 = msk1[r] ? 0.f : __expf((s1[r] + qr1[r]) * sc);
      lsum[r] += p0 + p1;
      plds[wid][quad * 4 + r][l15]      = f2bf(p0);
      plds[wid][quad * 4 + r][16 + l15] = f2bf(p1);
    }
    short8 ap = *(const short8*)&plds[wid][l15][quad * 8];
#pragma unroll
    for (int dt = 0; dt < 8; ++dt) O[dt] = MFMA16(ap, bv[dt], O[dt]);
  }

  // single end-of-kernel l reduction over the 16-lane k-groups
#pragma unroll
  for (int r = 0; r < 4; ++r) {
    float s = lsum[r];
    s += __shfl_xor(s, 1); s += __shfl_xor(s, 2);
    s += __shfl_xor(s, 4); s += __shfl_xor(s, 8);
    lsum[r] = s;
  }
#pragma unroll
  for (int r = 0; r < 4; ++r) {
    int q = q0 + quad * 4 + r;
    float inv = 1.f / lsum[r];
    short* orow = O2 + (b * 1024 + q) * 1024 + h;
#pragma unroll
    for (int dt = 0; dt < 8; ++dt) {
      int d = dt * 16 + l15;
      orow[d * 8] = f2bf(O[dt][r] * inv);
    }
  }
}

extern "C" void kernel_launch(void* const* d_in, const int* in_sizes, int n_in,
                              void* d_out, int out_size, void* d_ws, size_t ws_size,
                              hipStream_t stream) {
  const float* Q   = (const float*)d_in[0];
  const float* K   = (const float*)d_in[1];
  const float* V   = (const float*)d_in[2];
  const unsigned char* kpm = (const unsigned char*)d_in[4];
  const float* Wq  = (const float*)d_in[5];
  const float* Wk  = (const float*)d_in[6];
  const float* Wv  = (const float*)d_in[7];
  const float* Wo  = (const float*)d_in[8];
  const float* rel = (const float*)d_in[9];
  float* out = (float*)d_out;

  short* ws = (short*)d_ws;
  short* Qb   = ws;                      // 4194304
  short* Kb   = Qb + 4194304;
  short* Vb   = Kb + 4194304;
  short* Wqb  = Vb + 4194304;            // 1048576
  short* Wkb  = Wqb + 1048576;
  short* Wvb  = Wkb + 1048576;
  short* Wob  = Wvb + 1048576;
  short* relb = Wob + 1048576;           // 263168
  short* Qp   = relb + 263168;           // 4194304
  short* Kp   = Qp + 4194304;
  short* Vt   = Kp + 4194304;
  short* Qrel = Vt + 4194304;            // 8421376
  short* O2   = Qrel + 8421376;          // 4194304

  Cvt8 ca;
  ca.in[0] = Q;  ca.out[0] = Qb;
  ca.in[1] = K;  ca.out[1] = Kb;
  ca.in[2] = V;  ca.out[2] = Vb;
  ca.in[3] = Wq; ca.out[3] = Wqb;
  ca.in[4] = Wk; ca.out[4] = Wkb;
  ca.in[5] = Wv; ca.out[5] = Wvb;
  ca.in[6] = Wo; ca.out[6] = Wob;
  ca.in[7] = rel; ca.out[7] = relb;
  cvt8_k<<<dim3(16641), dim3(256), 0, stream>>>(ca);

  gemm_qkv<<<dim3(768), dim3(256), 0, stream>>>(Qb, Kb, Vb, Wqb, Wkb, Wvb, Qp, Kp, Vt);
  qrel_k<<<dim3(8704), dim3(256), 0, stream>>>(Qp, relb, Qrel);
  attn_k<<<dim3(512), dim3(256), 0, stream>>>(Qp, Kp, Vt, Qrel, kpm, O2);
  gemm_o<<<dim3(256), dim3(256), 0, stream>>>(O2, Wob, out);
}